// Round 11
// baseline (81.527 us; speedup 1.0000x reference)
//
#include <hip/hip_runtime.h>
#include <hip/hip_bf16.h>
#include <math.h>

#define NSP 4096   // H*W
#define CC  128    // channels
#define CIC 64     // inter channels
#define NB  4      // batch
#define LOG2E 1.4426950408889634f

typedef unsigned short u16;
typedef unsigned int u32;
typedef short s8bf __attribute__((ext_vector_type(8)));
typedef float f32x4 __attribute__((ext_vector_type(4)));
typedef float f32x2 __attribute__((ext_vector_type(2)));
typedef float f32x16 __attribute__((ext_vector_type(16)));

#define MFMA32(a, b, c) __builtin_amdgcn_mfma_f32_32x32x16_bf16(a, b, c, 0, 0, 0)

// workspace byte offsets
#define WSB_PB    0                              // bf16 [B][64][NSP] g channel-major
#define WSB_TH    (NB * CIC * NSP * 2)           // bf16 [B][NSP][64] theta*log2e token-major
#define WSB_PH    (WSB_TH + NB * NSP * CIC * 2)  // bf16 [B][NSP][64] phi token-major
#define WSB_OP    (WSB_PH + NB * NSP * CIC * 2)  // f32 [B][2][NSP][64] O partials (8MB)
#define WSB_LP    (WSB_OP + (size_t)NB * 2 * NSP * CIC * 4)  // f32 [B][2][NSP]
#define WSB_WT4   (WSB_LP + NB * 2 * NSP * 4)    // f32 [128][64][4] proj weights
#define WSB_WT2P  (WSB_WT4 + CC * 256 * 4)       // f32 [64][64][2] wconv weight pairs
#define WSB_PARTS (WSB_WT2P + CIC * CC * 4)      // f32 [128][4][2] stats partials

__device__ __forceinline__ u16 f2bf(float f) {
    union { float f; unsigned u; } v; v.f = f;
    unsigned r = v.u + 0x7fffu + ((v.u >> 16) & 1u);
    return (u16)(r >> 16);
}

// -------------------- Kernel 0: weight repack prep ------------------------------
__global__ __launch_bounds__(256) void prep_kernel(
    const float* __restrict__ g_w, const float* __restrict__ t_w,
    const float* __restrict__ p_w, const float* __restrict__ w_w,
    float* __restrict__ wT4, float* __restrict__ wT2p)
{
    const int c = blockIdx.x;
    const int o = threadIdx.x;
    if (o < 192) {
        float v;
        if (o < 64)       v = g_w[o * CC + c];
        else if (o < 128) v = t_w[(o - 64) * CC + c] * LOG2E;
        else              v = p_w[(o - 128) * CC + c];
        wT4[(c << 8) + ((o & 63) << 2) + (o >> 6)] = v;
    } else {
        wT4[(c << 8) + ((o - 192) << 2) + 3] = 0.f;
    }
    if (o < CIC)
        wT2p[(o << 7) + ((c & 63) << 1) + (c >> 6)] = w_w[c * CIC + o];
}

// -------------------- Kernel 1: fused 1x1 projections ---------------------------
// grid (NSP/32, NB), block 512. g -> PB cm; theta(log2e), phi -> token-major.
__global__ __launch_bounds__(512) void proj_kernel(
    const float* __restrict__ x, const float* __restrict__ wT4,
    const float* __restrict__ g_b, const float* __restrict__ t_b,
    const float* __restrict__ p_b,
    u16* __restrict__ PB, u16* __restrict__ th_tm, u16* __restrict__ ph_tm)
{
    __shared__ float Xs[CC][36];
    __shared__ u16 Ot[192][40];

    const int b    = blockIdx.y;
    const int n0   = blockIdx.x * 32;
    const int tid  = threadIdx.x;
    const int lane = tid & 63;
    const int wv   = tid >> 6;
    const int t0   = wv * 4;

    const float* xb = x + (size_t)b * CC * NSP + n0;
    #pragma unroll
    for (int k = 0; k < 2; ++k) {
        int idx = tid + (k << 9);
        int c = idx >> 3, t4 = (idx & 7) << 2;
        *(f32x4*)&Xs[c][t4] = *(const f32x4*)(xb + (size_t)c * NSP + t4);
    }
    __syncthreads();

    float acc[3][4];
    {
        float b0 = g_b[lane], b1 = t_b[lane] * LOG2E, b2 = p_b[lane];
        #pragma unroll
        for (int t = 0; t < 4; ++t) { acc[0][t] = b0; acc[1][t] = b1; acc[2][t] = b2; }
    }

    const float* wp = wT4 + (lane << 2);
    #pragma unroll 8
    for (int c = 0; c < CC; ++c) {
        f32x4 wv4 = *(const f32x4*)(wp + (c << 8));
        f32x4 xv  = *(const f32x4*)&Xs[c][t0];
        #pragma unroll
        for (int t = 0; t < 4; ++t) {
            acc[0][t] += wv4[0] * xv[t];
            acc[1][t] += wv4[1] * xv[t];
            acc[2][t] += wv4[2] * xv[t];
        }
    }

    #pragma unroll
    for (int p = 0; p < 3; ++p) {
        #pragma unroll
        for (int i = 0; i < 2; ++i) {
            unsigned pk = (unsigned)f2bf(acc[p][2 * i]) | ((unsigned)f2bf(acc[p][2 * i + 1]) << 16);
            *(unsigned*)&Ot[lane + 64 * p][t0 + 2 * i] = pk;
        }
    }
    __syncthreads();

    // g (rows 0..63) -> PB channel-major
    if (tid < 256) {
        int row = tid >> 2, ch = tid & 3;
        uint4 v = *(const uint4*)&Ot[row][ch * 8];
        *(uint4*)(PB + (size_t)b * CIC * NSP + (size_t)row * NSP + n0 + ch * 8) = v;
    }
    // theta (rows 64..127), phi (128..191) -> token-major
    {
        int tok = tid >> 4, sel = (tid >> 3) & 1, c8 = (tid & 7) * 8;
        u16* dst = (sel ? ph_tm : th_tm) + ((size_t)b * NSP + n0 + tok) * 64 + c8;
        union { u16 t[8]; uint4 v4; } u;
        #pragma unroll
        for (int j = 0; j < 8; ++j) u.t[j] = Ot[64 + sel * 64 + c8 + j][tok];
        *(uint4*)dst = u.v4;
    }
}

// -------------------- Kernel 2: MFMA attention, 64q-per-wave --------------------
// grid (NSP/128, 2 kv-splits, NB), block 256 = 4 waves: q-group s=w&1 (64 rows =
// 2x32), kv sub-half h=w>>1 (1024 tokens, 32 iters of KVBLK=32). K/V fragments
// loaded from LDS ONCE per iter, shared by both 32-q MFMAs (2x arithmetic
// intensity per LDS byte vs R10 -> LDS-BW bound time drops ~1.6x).
// Shift-softmax p=exp2(QK-32) via MFMA C-init; pack + shfl_xor(32) in regs.
__global__ __launch_bounds__(256, 2) void attn_kernel(
    const u16* __restrict__ PB, const u16* __restrict__ th_tm,
    const u16* __restrict__ ph_tm,
    float* __restrict__ O_part, float* __restrict__ l_part)
{
    const int b    = blockIdx.z;
    const int kvs  = blockIdx.y;
    const int q0   = blockIdx.x << 7;
    const int tid  = threadIdx.x;
    const int lane = tid & 63;
    const int w    = tid >> 6;       // 0..3
    const int s    = w & 1;          // q 64-group
    const int h    = w >> 1;         // kv half of this block's 2048 range
    const int l31  = lane & 31;
    const int l5   = lane >> 5;

    // [dbuf][K=0/V=1][half][4KB]: K tile = [32 kv][128B swz]; V tile = [64 ci][64B swz]
    __shared__ __align__(16) char KVb[2][2][2][4096];   // 32 KB
    __shared__ float Lm[128];

    const u16* gp = PB + (size_t)b * CIC * NSP;         // g cm [64][NSP]
    const u16* th = th_tm + (size_t)b * NSP * 64;       // theta tm
    const u16* ph = ph_tm + (size_t)b * NSP * 64;       // phi tm

    const int kb0 = kvs << 11;                          // 2048-token range

    // staging roles
    const int krow = tid >> 3;        // 0..31 (K row = kv token, 128B)
    const int kch  = tid & 7;
    const int vrow = tid >> 2;        // 0..63 (V row = ci, 64B)
    const int vch  = tid & 3;
    const int kdst = krow * 128 + (((kch ^ (krow & 7)) & 7) << 4);
    const int vdst = vrow * 64  + ((vch ^ (vrow & 3)) << 4);

    float4 rK0, rK1, rV0, rV1;
    auto load_t = [&](int t) {
        const int m0 = kb0 + (t << 5);
        rK0 = *(const float4*)(ph + ((size_t)(m0 + krow) << 6) + (kch << 3));
        rK1 = *(const float4*)(ph + ((size_t)(m0 + 1024 + krow) << 6) + (kch << 3));
        rV0 = *(const float4*)(gp + (size_t)vrow * NSP + m0 + (vch << 3));
        rV1 = *(const float4*)(gp + (size_t)vrow * NSP + m0 + 1024 + (vch << 3));
    };
    auto write_t = [&](int buf) {
        *(float4*)(&KVb[buf][0][0][0] + kdst) = rK0;
        *(float4*)(&KVb[buf][0][1][0] + kdst) = rK1;
        *(float4*)(&KVb[buf][1][0][0] + vdst) = rV0;
        *(float4*)(&KVb[buf][1][1][0] + vdst) = rV1;
    };

    // Q B-fragments (once): 2 q-groups x 4 frags
    s8bf qb0[4], qb1[4];
    {
        const int qt0 = q0 + (s << 6) + l31;
        const int qt1 = qt0 + 32;
        #pragma unroll
        for (int fc = 0; fc < 4; ++fc) {
            qb0[fc] = *(const s8bf*)(th + ((size_t)qt0 << 6) + fc * 16 + l5 * 8);
            qb1[fc] = *(const s8bf*)(th + ((size_t)qt1 << 6) + fc * 16 + l5 * 8);
        }
    }

    f32x16 Ov00, Ov01, Ov10, Ov11, cinit;
    #pragma unroll
    for (int i = 0; i < 16; ++i) {
        Ov00[i] = 0.f; Ov01[i] = 0.f; Ov10[i] = 0.f; Ov11[i] = 0.f;
        cinit[i] = -32.f;
    }
    float lr0 = 0.f, lr1 = 0.f;

    load_t(0); write_t(0); load_t(1);
    __syncthreads();

    u32 pk0[4][2], pk1[4][2];
    const int krd = l31 * 128;          // K read row base
    const int ksw = l31 & 7;
    const int vrd0 = l31 * 64;          // V read rows (ci, ci+32)
    const int vrd1 = (l31 + 32) * 64;
    const int vsw = l31 & 3;

    for (int t = 0; t < 32; ++t) {
        const int buf = t & 1;

        // ---- stage next tile first (regs from prev load), issue t+2 ----
        if (t < 31) write_t(buf ^ 1);
        if (t < 30) load_t(t + 2);

        const char* Kb = &KVb[buf][0][h][0];
        const char* Vb = &KVb[buf][1][h][0];

        // ---- QK^T: K frags loaded once, both q-groups ----
        f32x16 sv0 = cinit, sv1 = cinit;
        __builtin_amdgcn_s_setprio(1);
        #pragma unroll
        for (int fc = 0; fc < 4; ++fc) {
            s8bf ka = *(const s8bf*)(Kb + krd + (((2 * fc + l5) ^ ksw) << 4));
            sv0 = MFMA32(ka, qb0[fc], sv0);
            sv1 = MFMA32(ka, qb1[fc], sv1);
        }
        __builtin_amdgcn_s_setprio(0);

        // ---- shift-softmax: p = exp2(s), per-lane pack ----
        {
            float e[16];
            #pragma unroll
            for (int i = 0; i < 16; ++i) e[i] = __builtin_amdgcn_exp2f(sv0[i]);
            #pragma unroll
            for (int i = 0; i < 16; ++i) lr0 += e[i];
            #pragma unroll
            for (int m = 0; m < 4; ++m)
                #pragma unroll
                for (int i = 0; i < 2; ++i) {
                    __hip_bfloat162 hh = __float22bfloat162_rn(
                        make_float2(e[4 * m + 2 * i], e[4 * m + 2 * i + 1]));
                    union { __hip_bfloat162 h2; u32 u; } cv; cv.h2 = hh;
                    pk0[m][i] = cv.u;
                }
        }
        {
            float e[16];
            #pragma unroll
            for (int i = 0; i < 16; ++i) e[i] = __builtin_amdgcn_exp2f(sv1[i]);
            #pragma unroll
            for (int i = 0; i < 16; ++i) lr1 += e[i];
            #pragma unroll
            for (int m = 0; m < 4; ++m)
                #pragma unroll
                for (int i = 0; i < 2; ++i) {
                    __hip_bfloat162 hh = __float22bfloat162_rn(
                        make_float2(e[4 * m + 2 * i], e[4 * m + 2 * i + 1]));
                    union { __hip_bfloat162 h2; u32 u; } cv; cv.h2 = hh;
                    pk1[m][i] = cv.u;
                }
        }

        // ---- PV: V frags loaded once per f, shared by both q-groups ----
        __builtin_amdgcn_s_setprio(1);
        #pragma unroll
        for (int f = 0; f < 2; ++f) {
            s8bf v0 = *(const s8bf*)(Vb + vrd0 + (((2 * f + l5) ^ vsw) << 4));
            s8bf v1 = *(const s8bf*)(Vb + vrd1 + (((2 * f + l5) ^ vsw) << 4));
            // group 0 exchange
            {
                u32 sA0 = pk0[2 * f][0],     sA1 = pk0[2 * f][1];
                u32 sB0 = pk0[2 * f + 1][0], sB1 = pk0[2 * f + 1][1];
                u32 self0 = l5 ? sB0 : sA0, self1 = l5 ? sB1 : sA1;
                u32 send0 = l5 ? sA0 : sB0, send1 = l5 ? sA1 : sB1;
                u32 x0 = (u32)__shfl_xor((int)send0, 32);
                u32 x1 = (u32)__shfl_xor((int)send1, 32);
                union { u32 u[4]; s8bf v; } pa;
                pa.u[0] = l5 ? x0 : self0;
                pa.u[1] = l5 ? x1 : self1;
                pa.u[2] = l5 ? self0 : x0;
                pa.u[3] = l5 ? self1 : x1;
                Ov00 = MFMA32(pa.v, v0, Ov00);
                Ov01 = MFMA32(pa.v, v1, Ov01);
            }
            // group 1 exchange
            {
                u32 sA0 = pk1[2 * f][0],     sA1 = pk1[2 * f][1];
                u32 sB0 = pk1[2 * f + 1][0], sB1 = pk1[2 * f + 1][1];
                u32 self0 = l5 ? sB0 : sA0, self1 = l5 ? sB1 : sA1;
                u32 send0 = l5 ? sA0 : sB0, send1 = l5 ? sA1 : sB1;
                u32 x0 = (u32)__shfl_xor((int)send0, 32);
                u32 x1 = (u32)__shfl_xor((int)send1, 32);
                union { u32 u[4]; s8bf v; } pa;
                pa.u[0] = l5 ? x0 : self0;
                pa.u[1] = l5 ? x1 : self1;
                pa.u[2] = l5 ? self0 : x0;
                pa.u[3] = l5 ? self1 : x1;
                Ov10 = MFMA32(pa.v, v0, Ov10);
                Ov11 = MFMA32(pa.v, v1, Ov11);
            }
        }
        __builtin_amdgcn_s_setprio(0);

        __syncthreads();
    }

    // ---- merge the 2 sub-halves via LDS (recast KVb = 32KB = [128][64] f32) ----
    float lrh0 = lr0 + __shfl_xor(lr0, 32);
    float lrh1 = lr1 + __shfl_xor(lr1, 32);
    float* Olds = (float*)&KVb[0][0][0][0];

    if (h == 1) {
        #pragma unroll
        for (int reg = 0; reg < 16; ++reg) {
            int q = (reg & 3) + 8 * (reg >> 2) + 4 * l5;
            int r0 = (s << 6) + q;
            Olds[(r0)*64 + l31]           = Ov00[reg];
            Olds[(r0)*64 + 32 + l31]      = Ov01[reg];
            Olds[(r0 + 32) * 64 + l31]      = Ov10[reg];
            Olds[(r0 + 32) * 64 + 32 + l31] = Ov11[reg];
        }
        if (l5 == 0) {
            Lm[(s << 6) + l31]      = lrh0;
            Lm[(s << 6) + 32 + l31] = lrh1;
        }
    }
    __syncthreads();
    if (h == 0) {
        float lt0 = lrh0 + Lm[(s << 6) + l31];
        float lt1 = lrh1 + Lm[(s << 6) + 32 + l31];
        float* Ob = O_part + ((size_t)b * 2 + kvs) * NSP * 64;
        #pragma unroll
        for (int reg = 0; reg < 16; ++reg) {
            int q = (reg & 3) + 8 * (reg >> 2) + 4 * l5;
            int r0 = (s << 6) + q;
            int qg0 = q0 + r0, qg1 = q0 + r0 + 32;
            Ob[(size_t)qg0 * 64 + l31]      = Ov00[reg] + Olds[(r0)*64 + l31];
            Ob[(size_t)qg0 * 64 + 32 + l31] = Ov01[reg] + Olds[(r0)*64 + 32 + l31];
            Ob[(size_t)qg1 * 64 + l31]      = Ov10[reg] + Olds[(r0 + 32) * 64 + l31];
            Ob[(size_t)qg1 * 64 + 32 + l31] = Ov11[reg] + Olds[(r0 + 32) * 64 + 32 + l31];
        }
        if (l5 == 0) {
            float* Lb = l_part + ((size_t)b * 2 + kvs) * NSP + q0;
            Lb[(s << 6) + l31]      = lt0;
            Lb[(s << 6) + 32 + l31] = lt1;
        }
    }
}

// -------------------- Kernel 3: combine partials + W conv -> d_out --------------
__global__ __launch_bounds__(256) void wconv_kernel(
    const float* __restrict__ O_part, const float* __restrict__ l_part,
    const float* __restrict__ wT2p, const float* __restrict__ w_b,
    float* __restrict__ out)
{
    __shared__ float Ys[CIC][36];
    __shared__ float Of[CC][36];

    const int b    = blockIdx.y;
    const int n0   = blockIdx.x * 32;
    const int tid  = threadIdx.x;
    const int lane = tid & 63;
    const int wv   = tid >> 6;
    const int t0   = wv * 8;

    #pragma unroll
    for (int rnd = 0; rnd < 2; ++rnd) {
        int tok = (tid >> 4) + (rnd << 4);
        int ci4 = tid & 15;
        int qg  = n0 + tok;
        f32x4 a = {0.f, 0.f, 0.f, 0.f};
        float ls = 0.f;
        #pragma unroll
        for (int kvs = 0; kvs < 2; ++kvs) {
            a += *(const f32x4*)(O_part + (((size_t)b * 2 + kvs) * NSP + qg) * 64 + (ci4 << 2));
            ls += l_part[((size_t)b * 2 + kvs) * NSP + qg];
        }
        float inv = 1.0f / ls;
        #pragma unroll
        for (int j = 0; j < 4; ++j) Ys[(ci4 << 2) + j][tok] = a[j] * inv;
    }
    __syncthreads();

    float acc[2][8];
    #pragma unroll
    for (int t = 0; t < 8; ++t) { acc[0][t] = 0.f; acc[1][t] = 0.f; }

    const float* wp = wT2p + (lane << 1);
    #pragma unroll 8
    for (int ci = 0; ci < CIC; ++ci) {
        f32x2 wv2 = *(const f32x2*)(wp + (ci << 7));
        f32x4 y0 = *(const f32x4*)&Ys[ci][t0];
        f32x4 y1 = *(const f32x4*)&Ys[ci][t0 + 4];
        #pragma unroll
        for (int t = 0; t < 4; ++t) {
            acc[0][t]     += wv2[0] * y0[t];
            acc[0][4 + t] += wv2[0] * y1[t];
            acc[1][t]     += wv2[1] * y0[t];
            acc[1][4 + t] += wv2[1] * y1[t];
        }
    }

    float b0 = w_b[lane], b1 = w_b[64 + lane];
    #pragma unroll
    for (int t = 0; t < 4; ++t) {
        Of[lane][t0 + t]          = acc[0][t] + b0;
        Of[lane][t0 + 4 + t]      = acc[0][4 + t] + b0;
        Of[64 + lane][t0 + t]     = acc[1][t] + b1;
        Of[64 + lane][t0 + 4 + t] = acc[1][4 + t] + b1;
    }
    __syncthreads();

    float* ob = out + (size_t)b * CC * NSP + n0;
    #pragma unroll
    for (int k = 0; k < 4; ++k) {
        int idx = tid + (k << 8);
        int row = idx >> 3, ch = idx & 7;
        *(float4*)(ob + (size_t)row * NSP + ch * 4) = *(const float4*)&Of[row][ch * 4];
    }
}

// -------------------- Kernel 4: per-channel partial stats -----------------------
__global__ __launch_bounds__(256) void stats_kernel(
    const float* __restrict__ wy, float* __restrict__ parts)
{
    const int c   = blockIdx.x >> 2;
    const int qd  = blockIdx.x & 3;
    const int tid = threadIdx.x;
    float s = 0.f, ss = 0.f;
    #pragma unroll 4
    for (int k = 0; k < 16; ++k) {
        int i = qd * 4096 + k * 256 + tid;
        int b = i >> 12, n = i & (NSP - 1);
        float v = wy[((size_t)b * CC + c) * NSP + n];
        s += v; ss += v * v;
    }
    #pragma unroll
    for (int off = 32; off > 0; off >>= 1) {
        s  += __shfl_down(s, off, 64);
        ss += __shfl_down(ss, off, 64);
    }
    __shared__ float sred[4], ssred[4];
    const int wid = tid >> 6, lane = tid & 63;
    if (lane == 0) { sred[wid] = s; ssred[wid] = ss; }
    __syncthreads();
    if (tid == 0) {
        parts[(c * 4 + qd) * 2]     = sred[0] + sred[1] + sred[2] + sred[3];
        parts[(c * 4 + qd) * 2 + 1] = ssred[0] + ssred[1] + ssred[2] + ssred[3];
    }
}

// -------------------- Kernel 5: BN finalize + residual (in-place) ---------------
__global__ __launch_bounds__(256) void bn_kernel(
    const float* __restrict__ x, const float* __restrict__ parts,
    const float* __restrict__ gamma, const float* __restrict__ beta,
    float* __restrict__ out)
{
    const int i = blockIdx.x * 256 + threadIdx.x;
    const int c = (i >> 10) & (CC - 1);
    float s  = parts[c * 8]     + parts[c * 8 + 2] + parts[c * 8 + 4] + parts[c * 8 + 6];
    float ss = parts[c * 8 + 1] + parts[c * 8 + 3] + parts[c * 8 + 5] + parts[c * 8 + 7];
    float mean = s * (1.0f / 16384.0f);
    float var  = ss * (1.0f / 16384.0f) - mean * mean;
    float istd = rsqrtf(var + 1e-5f);
    float ga = gamma[c] * istd;
    float be = beta[c] - mean * ga;
    float4 wy = ((const float4*)out)[i];
    float4 xv = ((const float4*)x)[i];
    float4 o;
    o.x = wy.x * ga + be + xv.x;
    o.y = wy.y * ga + be + xv.y;
    o.z = wy.z * ga + be + xv.z;
    o.w = wy.w * ga + be + xv.w;
    ((float4*)out)[i] = o;
}

extern "C" void kernel_launch(void* const* d_in, const int* in_sizes, int n_in,
                              void* d_out, int out_size, void* d_ws, size_t ws_size,
                              hipStream_t stream)
{
    const float* x    = (const float*)d_in[0];
    const float* g_w  = (const float*)d_in[1];
    const float* g_b  = (const float*)d_in[2];
    const float* t_w  = (const float*)d_in[3];
    const float* t_b  = (const float*)d_in[4];
    const float* p_w  = (const float*)d_in[5];
    const float* p_b  = (const float*)d_in[6];
    const float* w_w  = (const float*)d_in[7];
    const float* w_b  = (const float*)d_in[8];
    const float* bn_g = (const float*)d_in[9];
    const float* bn_b = (const float*)d_in[10];
    float* out = (float*)d_out;
    char* ws8  = (char*)d_ws;

    u16*   PB    = (u16*)(ws8 + WSB_PB);
    u16*   TH    = (u16*)(ws8 + WSB_TH);
    u16*   PH    = (u16*)(ws8 + WSB_PH);
    float* OP    = (float*)(ws8 + WSB_OP);
    float* LP    = (float*)(ws8 + WSB_LP);
    float* wT4   = (float*)(ws8 + WSB_WT4);
    float* wT2p  = (float*)(ws8 + WSB_WT2P);
    float* parts = (float*)(ws8 + WSB_PARTS);

    prep_kernel <<<dim3(CC), 256, 0, stream>>>(g_w, t_w, p_w, w_w, wT4, wT2p);
    proj_kernel <<<dim3(NSP / 32, NB), 512, 0, stream>>>(x, wT4, g_b, t_b, p_b, PB, TH, PH);
    attn_kernel <<<dim3(NSP / 128, 2, NB), 256, 0, stream>>>(PB, TH, PH, OP, LP);
    wconv_kernel<<<dim3(NSP / 32, NB), 256, 0, stream>>>(OP, LP, wT2p, w_b, out);
    stats_kernel<<<dim3(CC * 4), 256, 0, stream>>>(out, parts);
    bn_kernel   <<<dim3(2048), 256, 0, stream>>>(x, parts, bn_g, bn_b, out);
}